// Round 2
// baseline (408.541 us; speedup 1.0000x reference)
//
#include <hip/hip_runtime.h>
#include <hip/hip_cooperative_groups.h>
#include <math.h>

namespace cg = cooperative_groups;

// Problem constants (match reference)
#define B 32
#define P (360*640)        // 230400 pixels per batch
#define L 5
#define DELTA_V 1.0f
#define DELTA_D 6.0f

#define G4 (P/4)           // 57600 int4/float4 groups per batch
#define CHUNKS 64          // contiguous chunks per batch
#define NT (B*CHUNKS)      // 2048 fixed tiles
#define CG 900             // groups per chunk (G4/CHUNKS)
#define NVP 32             // padded per-tile partial stride (25 used)

__device__ __forceinline__ float waveReduce(float v) {
#pragma unroll
    for (int off = 32; off; off >>= 1) v += __shfl_down(v, off, 64);
    return v;
}

// Single fused cooperative kernel:
//   phase 1: per-tile segment sums/counts (deterministic partials)
//   phase 2: segment means + valid
//   phase 3: pull (variance) loss per tile
//   phase 4: block 0 — push loss, point_count, final combine
// __launch_bounds__(256,4): cap 128 VGPRs so the x2-unrolled load groups
// (10 x 16B in flight per wave) actually get registers instead of being
// serialized (previous build: VGPR_Count=32 -> load serialization -> 2.2 TB/s).
__global__ __launch_bounds__(256, 4) void fused_k(const int* __restrict__ tgt,
                                                  const float* __restrict__ emb,
                                                  float* ws, float* out) {
    cg::grid_group gg = cg::this_grid();
    const int tid  = threadIdx.x;
    const int lane = tid & 63, wave = tid >> 6;
    const int nb   = gridDim.x;

    float* part   = ws;                   // NT*NVP floats
    float* means  = part + (size_t)NT*NVP;// B*L*4
    float* validf = means + B*L*4;        // B*L
    float* cntv   = validf + B*L;         // B*L (valid ? count : 0)
    float* pullp  = cntv + B*L;           // NT

    __shared__ float  red[4][32];
    __shared__ float4 lmean[8];
    __shared__ float  lvalid[8];

    // ===================== phase 1: segment sums =====================
    for (int tile = blockIdx.x; tile < NT; tile += nb) {
        const int b  = tile >> 6;
        const int gs = (tile & 63) * CG, ge = gs + CG;
        const int4*   t4 = (const int4*)(tgt + (size_t)b * P);
        const float4* e0 = (const float4*)(emb + (size_t)(b*4+0) * P);
        const float4* e1 = (const float4*)(emb + (size_t)(b*4+1) * P);
        const float4* e2 = (const float4*)(emb + (size_t)(b*4+2) * P);
        const float4* e3 = (const float4*)(emb + (size_t)(b*4+3) * P);

        float s[L][4], cn[L];
#pragma unroll
        for (int l = 0; l < L; ++l) { cn[l]=0.f; s[l][0]=s[l][1]=s[l][2]=s[l][3]=0.f; }

        auto proc = [&](int tt, float x0, float x1, float x2, float x3) {
#pragma unroll
            for (int l = 0; l < L; ++l) {
                float m = (tt == l+1) ? 1.f : 0.f;
                cn[l] += m;
                s[l][0] = fmaf(m, x0, s[l][0]);
                s[l][1] = fmaf(m, x1, s[l][1]);
                s[l][2] = fmaf(m, x2, s[l][2]);
                s[l][3] = fmaf(m, x3, s[l][3]);
            }
        };

        // x2 unrolled: issue all 10 vector loads before consuming (MLP)
        for (int g0 = gs + tid; g0 < ge; g0 += 512) {
            const int g1  = g0 + 256;
            const int gg1 = (g1 < ge) ? g1 : g0;    // safe duplicate address
            int4   t0v = t4[g0],  t1v = t4[gg1];
            float4 a00 = e0[g0],  a01 = e1[g0],  a02 = e2[g0],  a03 = e3[g0];
            float4 a10 = e0[gg1], a11 = e1[gg1], a12 = e2[gg1], a13 = e3[gg1];
            if (g1 >= ge) { t1v.x = 0; t1v.y = 0; t1v.z = 0; t1v.w = 0; } // label 0 -> no lane match
            proc(t0v.x, a00.x, a01.x, a02.x, a03.x);
            proc(t0v.y, a00.y, a01.y, a02.y, a03.y);
            proc(t0v.z, a00.z, a01.z, a02.z, a03.z);
            proc(t0v.w, a00.w, a01.w, a02.w, a03.w);
            proc(t1v.x, a10.x, a11.x, a12.x, a13.x);
            proc(t1v.y, a10.y, a11.y, a12.y, a13.y);
            proc(t1v.z, a10.z, a11.z, a12.z, a13.z);
            proc(t1v.w, a10.w, a11.w, a12.w, a13.w);
        }

        float vals[25];
#pragma unroll
        for (int l = 0; l < L; ++l) {
            vals[l*4+0]=s[l][0]; vals[l*4+1]=s[l][1];
            vals[l*4+2]=s[l][2]; vals[l*4+3]=s[l][3];
            vals[20+l]=cn[l];
        }
#pragma unroll
        for (int k = 0; k < 25; ++k) {
            float r = waveReduce(vals[k]);
            if (lane == 0) red[wave][k] = r;
        }
        __syncthreads();
        if (tid < 25)
            part[(size_t)tile*NVP + tid] = red[0][tid]+red[1][tid]+red[2][tid]+red[3][tid];
        __syncthreads();   // protect red[] before next tile
    }
    gg.sync();

    // ===================== phase 2: means/valid =====================
    for (int sg = blockIdx.x; sg < B*L; sg += nb) {
        if (tid < 64) {
            const int bb = sg / L, l = sg % L;
            const float* pp = part + (size_t)(bb*CHUNKS + tid) * NVP;
            float v0=pp[l*4+0], v1=pp[l*4+1], v2=pp[l*4+2], v3=pp[l*4+3], vc=pp[20+l];
            v0=waveReduce(v0); v1=waveReduce(v1); v2=waveReduce(v2);
            v3=waveReduce(v3); vc=waveReduce(vc);
            if (lane == 0) {
                const float inv = 1.f / fmaxf(vc, 1.f);
                const bool  vl  = vc > 1.5f;          // integer count > 1
                means[sg*4+0]=v0*inv; means[sg*4+1]=v1*inv;
                means[sg*4+2]=v2*inv; means[sg*4+3]=v3*inv;
                validf[sg] = vl ? 1.f : 0.f;
                cntv[sg]   = vl ? vc  : 0.f;
            }
        }
    }
    gg.sync();

    // ===================== phase 3: pull loss =====================
    for (int tile = blockIdx.x; tile < NT; tile += nb) {
        const int b  = tile >> 6;
        const int gs = (tile & 63) * CG, ge = gs + CG;
        __syncthreads();   // protect lmean/red from previous tile
        if (tid == 0) { lmean[0] = make_float4(0.f,0.f,0.f,0.f); lvalid[0] = 0.f; }
        else if (tid <= L) {
            lmean[tid]  = *(const float4*)(means + ((size_t)b*L + tid-1)*4);
            lvalid[tid] = validf[b*L + tid-1];
        }
        __syncthreads();

        const int4*   t4 = (const int4*)(tgt + (size_t)b * P);
        const float4* e0 = (const float4*)(emb + (size_t)(b*4+0) * P);
        const float4* e1 = (const float4*)(emb + (size_t)(b*4+1) * P);
        const float4* e2 = (const float4*)(emb + (size_t)(b*4+2) * P);
        const float4* e3 = (const float4*)(emb + (size_t)(b*4+3) * P);

        float acc = 0.f;
        auto proc3 = [&](int tt, float x0, float x1, float x2, float x3) {
            float4 m = lmean[tt];
            float d0 = x0-m.x, d1 = x1-m.y, d2 = x2-m.z, d3 = x3-m.w;
            float sq   = d0*d0 + d1*d1 + d2*d2 + d3*d3;
            float dist = sqrtf(fmaxf(sq, 1e-12f));
            float h    = fmaxf(dist - DELTA_V, 0.f);
            acc = fmaf(lvalid[tt]*h, h, acc);
        };

        for (int g0 = gs + tid; g0 < ge; g0 += 512) {
            const int g1  = g0 + 256;
            const int gg1 = (g1 < ge) ? g1 : g0;
            int4   t0v = t4[g0],  t1v = t4[gg1];
            float4 a00 = e0[g0],  a01 = e1[g0],  a02 = e2[g0],  a03 = e3[g0];
            float4 a10 = e0[gg1], a11 = e1[gg1], a12 = e2[gg1], a13 = e3[gg1];
            if (g1 >= ge) { t1v.x = 0; t1v.y = 0; t1v.z = 0; t1v.w = 0; } // lvalid[0]=0 -> no contrib
            proc3(t0v.x, a00.x, a01.x, a02.x, a03.x);
            proc3(t0v.y, a00.y, a01.y, a02.y, a03.y);
            proc3(t0v.z, a00.z, a01.z, a02.z, a03.z);
            proc3(t0v.w, a00.w, a01.w, a02.w, a03.w);
            proc3(t1v.x, a10.x, a11.x, a12.x, a13.x);
            proc3(t1v.y, a10.y, a11.y, a12.y, a13.y);
            proc3(t1v.z, a10.z, a11.z, a12.z, a13.z);
            proc3(t1v.w, a10.w, a11.w, a12.w, a13.w);
        }

        float r = waveReduce(acc);
        if (lane == 0) red[wave][0] = r;
        __syncthreads();
        if (tid == 0) pullp[tile] = red[0][0]+red[1][0]+red[2][0]+red[3][0];
    }
    gg.sync();

    // ===================== phase 4: finale (block 0) =====================
    if (blockIdx.x != 0) return;

    float vb = 0.f, has = 0.f;
    if (tid < B) {
        const float* mb = means  + tid*L*4;
        const float* vv = validf + tid*L;
        float ssum = 0.f, np = 0.f;
#pragma unroll
        for (int i = 0; i < L; ++i)
#pragma unroll
            for (int j = i+1; j < L; ++j) {
                float ok = vv[i]*vv[j];
                float d0 = mb[i*4+0]-mb[j*4+0];
                float d1 = mb[i*4+1]-mb[j*4+1];
                float d2 = mb[i*4+2]-mb[j*4+2];
                float d3 = mb[i*4+3]-mb[j*4+3];
                float psq = d0*d0 + d1*d1 + d2*d2 + d3*d3;
                float pd  = sqrtf(fmaxf(psq, 1e-12f));
                float ph  = fmaxf(DELTA_D - pd, 0.f);
                ssum += ok*ph*ph;
                np   += ok;
            }
        if (np > 0.f) { vb = ssum/np; has = 1.f; }
    }
    float pc = (tid < B*L) ? cntv[tid] : 0.f;
    float ps = 0.f;
    for (int i = tid; i < NT; i += 256) ps += pullp[i];

    float rvb = waveReduce(vb);
    float rhs = waveReduce(has);
    float rpc = waveReduce(pc);
    float rps = waveReduce(ps);
    if (lane == 0) { red[wave][0]=rvb; red[wave][1]=rhs; red[wave][2]=rpc; red[wave][3]=rps; }
    __syncthreads();
    if (tid == 0) {
        float svb = red[0][0]+red[1][0]+red[2][0]+red[3][0];
        float shs = red[0][1]+red[1][1]+red[2][1]+red[3][1];
        float spc = red[0][2]+red[1][2]+red[2][2]+red[3][2];
        float sps = red[0][3]+red[1][3]+red[2][3]+red[3][3];
        float var = (shs > 0.f) ? svb/shs : 0.f;               // push loss
        float dl  = (spc > 0.f) ? sps/fmaxf(spc, 1.f) : 0.f;   // pull loss
        out[0] = dl + var;
    }
}

// ---------------------------------------------------------------------------
extern "C" void kernel_launch(void* const* d_in, const int* in_sizes, int n_in,
                              void* d_out, int out_size, void* d_ws, size_t ws_size,
                              hipStream_t stream) {
    const int*   tgt = (const int*)d_in[0];    // targets int32 [B,H,W]
    const float* emb = (const float*)d_in[1];  // embedding fp32 [B,C,H,W]
    float* ws  = (float*)d_ws;                 // ~275 KB used
    float* out = (float*)d_out;

    // Size the cooperative grid to guaranteed co-residency (occupancy query is
    // a pure host-side query: capture-safe, same value every call).
    int maxB = 4;
    (void)hipOccupancyMaxActiveBlocksPerMultiprocessor(&maxB, fused_k, 256, 0);
    if (maxB < 1) maxB = 1;
    int grid = maxB * 256;                     // 256 CUs on MI355X
    if (grid > NT) grid = NT;

    void* args[] = {(void*)&tgt, (void*)&emb, (void*)&ws, (void*)&out};
    (void)hipLaunchCooperativeKernel((void*)fused_k, dim3(grid), dim3(256),
                                     args, 0, stream);
}

// Round 4
// 225.987 us; speedup vs baseline: 1.8078x; 1.8078x over previous
//
#include <hip/hip_runtime.h>
#include <math.h>

// Problem constants (match reference)
#define B 32
#define C 4
#define H 360
#define W 640
#define P (H*W)            // 230400 pixels per batch
#define L 5                // MAX_LANES
#define DELTA_V 1.0f
#define DELTA_D 6.0f

#define NV 25              // per-block partial values: 20 sums (5 lanes x 4 ch) + 5 counts
#define BLK1 64            // blocks per batch for the streaming kernels
                           // grid = 64x32 = 2048 blocks = 8 blocks/CU: at VGPR=32 this
                           // reaches 32 waves/CU (round-1 used 1024 blocks -> 34% occupancy,
                           // latency-bound at 2.2 TB/s effective)
#define NBLK (B*BLK1)      // 2048 total streaming blocks
#define G4 (P/4)           // 57600 float4/int4 groups per batch

__device__ __forceinline__ float waveReduce(float v) {
#pragma unroll
    for (int off = 32; off; off >>= 1) v += __shfl_down(v, off, 64);
    return v;
}

// ---------------------------------------------------------------------------
// Kernel 1: per-(batch,lane) segment sums + counts, deterministic block partials
// ---------------------------------------------------------------------------
__global__ __launch_bounds__(256) void seg_sums_k(const int* __restrict__ tgt,
                                                  const float* __restrict__ emb,
                                                  float* __restrict__ part1) {
    const int b = blockIdx.y;
    float s[L][C];
    float cn[L];
#pragma unroll
    for (int l = 0; l < L; ++l) {
        cn[l] = 0.f;
#pragma unroll
        for (int c = 0; c < C; ++c) s[l][c] = 0.f;
    }

    const int4*   t4 = (const int4*)(tgt + (size_t)b * P);
    const float4* e0 = (const float4*)(emb + (size_t)(b*C + 0) * P);
    const float4* e1 = (const float4*)(emb + (size_t)(b*C + 1) * P);
    const float4* e2 = (const float4*)(emb + (size_t)(b*C + 2) * P);
    const float4* e3 = (const float4*)(emb + (size_t)(b*C + 3) * P);

    auto proc = [&](int tt, float x0, float x1, float x2, float x3) {
#pragma unroll
        for (int l = 0; l < L; ++l) {
            float m = (tt == l + 1) ? 1.0f : 0.0f;
            cn[l] += m;
            s[l][0] = fmaf(m, x0, s[l][0]);
            s[l][1] = fmaf(m, x1, s[l][1]);
            s[l][2] = fmaf(m, x2, s[l][2]);
            s[l][3] = fmaf(m, x3, s[l][3]);
        }
    };

    for (int g = blockIdx.x * 256 + threadIdx.x; g < G4; g += BLK1 * 256) {
        int4   t  = t4[g];
        float4 a0 = e0[g], a1 = e1[g], a2 = e2[g], a3 = e3[g];
        proc(t.x, a0.x, a1.x, a2.x, a3.x);
        proc(t.y, a0.y, a1.y, a2.y, a3.y);
        proc(t.z, a0.z, a1.z, a2.z, a3.z);
        proc(t.w, a0.w, a1.w, a2.w, a3.w);
    }

    // pack 25 values, wave-reduce each, then cross-wave via LDS
    float vals[NV];
#pragma unroll
    for (int l = 0; l < L; ++l) {
#pragma unroll
        for (int c = 0; c < C; ++c) vals[l*4 + c] = s[l][c];
        vals[20 + l] = cn[l];
    }

    __shared__ float red[4][NV];
    const int lane = threadIdx.x & 63, wave = threadIdx.x >> 6;
#pragma unroll
    for (int k = 0; k < NV; ++k) {
        float r = waveReduce(vals[k]);
        if (lane == 0) red[wave][k] = r;
    }
    __syncthreads();
    if (threadIdx.x < NV) {
        float r = red[0][threadIdx.x] + red[1][threadIdx.x]
                + red[2][threadIdx.x] + red[3][threadIdx.x];
        part1[(size_t)(b * BLK1 + blockIdx.x) * NV + threadIdx.x] = r;
    }
}

// ---------------------------------------------------------------------------
// Kernel 2: wave-per-segment partial reduction -> means / valid / count
// 160 segments, one wave each; lane = chunk index (coalesced over part1)
// ---------------------------------------------------------------------------
__global__ __launch_bounds__(256) void means_k(const float* __restrict__ part1,
                                               float* __restrict__ means,
                                               float* __restrict__ validf,
                                               float* __restrict__ cntv) {
    const int seg  = (blockIdx.x * 256 + threadIdx.x) >> 6;   // global wave id
    const int lane = threadIdx.x & 63;
    if (seg >= B * L) return;
    const int b = seg / L, l = seg % L;

    const float* p = part1 + (size_t)(b * BLK1 + lane) * NV;  // lane = chunk (BLK1==64)
    float v0 = p[l*4+0], v1 = p[l*4+1], v2 = p[l*4+2], v3 = p[l*4+3], vc = p[20+l];
    v0 = waveReduce(v0); v1 = waveReduce(v1); v2 = waveReduce(v2);
    v3 = waveReduce(v3); vc = waveReduce(vc);
    if (lane == 0) {
        const float inv = 1.0f / fmaxf(vc, 1.0f);
        const bool  v   = vc > 1.5f;    // integer count > 1
        means[seg*4+0] = v0 * inv;
        means[seg*4+1] = v1 * inv;
        means[seg*4+2] = v2 * inv;
        means[seg*4+3] = v3 * inv;
        validf[seg] = v ? 1.f : 0.f;
        cntv[seg]   = v ? vc  : 0.f;
    }
}

// ---------------------------------------------------------------------------
// Kernel 3: pull (variance) loss — per-pixel hinge distance to its lane mean
// ---------------------------------------------------------------------------
__global__ __launch_bounds__(256) void pull_k(const int* __restrict__ tgt,
                                              const float* __restrict__ emb,
                                              const float* __restrict__ means,
                                              const float* __restrict__ validf,
                                              float* __restrict__ part3) {
    __shared__ float4 lmean[L + 1];   // label 0 -> zero mean
    __shared__ float  lvalid[L + 1];  // label 0 -> invalid
    __shared__ float  lred[4];
    const int b = blockIdx.y;
    const int tid = threadIdx.x;

    if (tid == 0) { lmean[0] = make_float4(0.f, 0.f, 0.f, 0.f); lvalid[0] = 0.f; }
    else if (tid <= L) {
        lmean[tid]  = *(const float4*)(means + ((size_t)b*L + (tid-1)) * C);
        lvalid[tid] = validf[b*L + (tid-1)];
    }
    __syncthreads();

    const int4*   t4 = (const int4*)(tgt + (size_t)b * P);
    const float4* e0 = (const float4*)(emb + (size_t)(b*C + 0) * P);
    const float4* e1 = (const float4*)(emb + (size_t)(b*C + 1) * P);
    const float4* e2 = (const float4*)(emb + (size_t)(b*C + 2) * P);
    const float4* e3 = (const float4*)(emb + (size_t)(b*C + 3) * P);

    float acc = 0.f;
    auto proc = [&](int tt, float x0, float x1, float x2, float x3) {
        float4 m = lmean[tt];
        float d0 = x0 - m.x, d1 = x1 - m.y, d2 = x2 - m.z, d3 = x3 - m.w;
        float sq   = d0*d0 + d1*d1 + d2*d2 + d3*d3;
        float dist = sqrtf(fmaxf(sq, 1e-12f));
        float h    = fmaxf(dist - DELTA_V, 0.f);
        acc = fmaf(lvalid[tt] * h, h, acc);
    };

    for (int g = blockIdx.x * 256 + threadIdx.x; g < G4; g += BLK1 * 256) {
        int4   t  = t4[g];
        float4 a0 = e0[g], a1 = e1[g], a2 = e2[g], a3 = e3[g];
        proc(t.x, a0.x, a1.x, a2.x, a3.x);
        proc(t.y, a0.y, a1.y, a2.y, a3.y);
        proc(t.z, a0.z, a1.z, a2.z, a3.z);
        proc(t.w, a0.w, a1.w, a2.w, a3.w);
    }

    float r = waveReduce(acc);
    const int lane = tid & 63, wave = tid >> 6;
    if (lane == 0) lred[wave] = r;
    __syncthreads();
    if (tid == 0)
        part3[b * BLK1 + blockIdx.x] = lred[0] + lred[1] + lred[2] + lred[3];
}

// ---------------------------------------------------------------------------
// Kernel 4: final combine — push loss + point_count + pull partial sum
// ---------------------------------------------------------------------------
__global__ __launch_bounds__(256) void finish_k(const float* __restrict__ part3,
                                                const float* __restrict__ means,
                                                const float* __restrict__ validf,
                                                const float* __restrict__ cntv,
                                                float* __restrict__ out) {
    __shared__ float red[4][4];
    const int tid = threadIdx.x;
    const int lane = tid & 63, wave = tid >> 6;

    // push (distance) loss: one thread per batch over the 10 mean pairs
    float vb = 0.f, has = 0.f;
    if (tid < B) {
        const float* mb = means  + tid * L * 4;
        const float* vv = validf + tid * L;
        float ssum = 0.f, np = 0.f;
#pragma unroll
        for (int i = 0; i < L; ++i)
#pragma unroll
            for (int j = i + 1; j < L; ++j) {
                float ok = vv[i] * vv[j];
                float d0 = mb[i*4+0] - mb[j*4+0];
                float d1 = mb[i*4+1] - mb[j*4+1];
                float d2 = mb[i*4+2] - mb[j*4+2];
                float d3 = mb[i*4+3] - mb[j*4+3];
                float psq = d0*d0 + d1*d1 + d2*d2 + d3*d3;
                float pd  = sqrtf(fmaxf(psq, 1e-12f));
                float ph  = fmaxf(DELTA_D - pd, 0.f);
                ssum += ok * ph * ph;
                np   += ok;
            }
        if (np > 0.f) { vb = ssum / np; has = 1.f; }
    }
    float pc = (tid < B*L) ? cntv[tid] : 0.f;
    float ps = 0.f;
    for (int i = tid; i < NBLK; i += 256) ps += part3[i];

    float rvb = waveReduce(vb);
    float rhs = waveReduce(has);
    float rpc = waveReduce(pc);
    float rps = waveReduce(ps);
    if (lane == 0) { red[wave][0]=rvb; red[wave][1]=rhs; red[wave][2]=rpc; red[wave][3]=rps; }
    __syncthreads();
    if (tid == 0) {
        float svb = red[0][0]+red[1][0]+red[2][0]+red[3][0];
        float shs = red[0][1]+red[1][1]+red[2][1]+red[3][1];
        float spc = red[0][2]+red[1][2]+red[2][2]+red[3][2];
        float sps = red[0][3]+red[1][3]+red[2][3]+red[3][3];
        float var = (shs > 0.f) ? svb / shs : 0.f;              // push loss
        float dl  = (spc > 0.f) ? sps / fmaxf(spc, 1.f) : 0.f;  // pull loss
        out[0] = dl + var;
    }
}

// ---------------------------------------------------------------------------
extern "C" void kernel_launch(void* const* d_in, const int* in_sizes, int n_in,
                              void* d_out, int out_size, void* d_ws, size_t ws_size,
                              hipStream_t stream) {
    const int*   tgt = (const int*)d_in[0];    // targets int32 [B,H,W]
    const float* emb = (const float*)d_in[1];  // embedding fp32 [B,C,H,W]

    float* ws     = (float*)d_ws;
    float* part1  = ws;                         // NBLK*NV = 51200 floats
    float* means  = part1 + (size_t)NBLK * NV;  // 640 floats (byte off 204800, 16B-aligned)
    float* validf = means + B*L*C;              // 160 floats
    float* cntv   = validf + B*L;               // 160 floats
    float* part3  = cntv + B*L;                 // NBLK floats
    // total ws use: ~220 KB

    dim3 grid(BLK1, B);                         // 2048 blocks
    seg_sums_k<<<grid, 256, 0, stream>>>(tgt, emb, part1);
    means_k<<<(B*L + 3) / 4, 256, 0, stream>>>(part1, means, validf, cntv);  // 160 waves
    pull_k<<<grid, 256, 0, stream>>>(tgt, emb, means, validf, part3);
    finish_k<<<1, 256, 0, stream>>>(part3, means, validf, cntv, (float*)d_out);
}